// Round 1
// baseline (1834.523 us; speedup 1.0000x reference)
//
#include <hip/hip_runtime.h>
#include <hip/hip_bf16.h>

// ---------------------------------------------------------------------------
// Sizes (fixed by the problem)
// ---------------------------------------------------------------------------
// H=512, N=8, B=4, T=1024.  B*T = 4096 rows.  N*H = 4096.
// Q/K/V projections: (4096 x 512) @ (512 x 4096) -> (4096 x 4096)
// Attention: per (b,a) [32 of them], S = Qh(1024x512) @ Kh^T -> only need
//   per-row max, sum of exp(S/sqrt(512)), and the diagonal logit.
// hh = diag(attn) * V  (elementwise row scale, same buffer layout as needed
//   for the Wo GEMM because both reshapes are raw row-major reinterprets).
// ---------------------------------------------------------------------------

#define LN_EPS 1e-5f

// ---------------------------------------------------------------------------
// Generic tiled f32 GEMM: C = act(A[M,K] @ W[K,N] + bias)
// 64x64 tile, BK=16, 256 threads, 4x4 micro-tile per thread.
// ---------------------------------------------------------------------------
template <bool BIAS, bool RELU>
__global__ __launch_bounds__(256) void gemm64(const float* __restrict__ A,
                                              const float* __restrict__ W,
                                              const float* __restrict__ bias,
                                              float* __restrict__ C,
                                              int M, int N, int K) {
    __shared__ float As[16][64];   // [k][m]
    __shared__ float Ws[16][64];   // [k][n]
    const int tid = threadIdx.x;
    const int tx = tid & 15;        // 0..15 -> col group
    const int ty = tid >> 4;        // 0..15 -> row group
    const int row0 = blockIdx.y * 64;
    const int col0 = blockIdx.x * 64;

    // A-tile load mapping: 64 rows x 16 k, one float4 along k per thread
    const int am = tid >> 2;          // 0..63 row in tile
    const int ak = (tid & 3) * 4;     // 0,4,8,12
    // W-tile load mapping: 16 k x 64 n, one float4 along n per thread
    const int wk = tid >> 4;          // 0..15
    const int wn = (tid & 15) * 4;    // 0..60

    float acc[4][4] = {};

    for (int kk = 0; kk < K; kk += 16) {
        __syncthreads();
        float4 av = *(const float4*)&A[(row0 + am) * K + kk + ak];
        As[ak + 0][am] = av.x;
        As[ak + 1][am] = av.y;
        As[ak + 2][am] = av.z;
        As[ak + 3][am] = av.w;
        *(float4*)&Ws[wk][wn] = *(const float4*)&W[(kk + wk) * N + col0 + wn];
        __syncthreads();
#pragma unroll
        for (int k = 0; k < 16; ++k) {
            float4 a4 = *(const float4*)&As[k][ty * 4];
            float4 b4 = *(const float4*)&Ws[k][tx * 4];
            const float a[4] = {a4.x, a4.y, a4.z, a4.w};
            const float b[4] = {b4.x, b4.y, b4.z, b4.w};
#pragma unroll
            for (int i = 0; i < 4; ++i)
#pragma unroll
                for (int j = 0; j < 4; ++j)
                    acc[i][j] = fmaf(a[i], b[j], acc[i][j]);
        }
    }

#pragma unroll
    for (int i = 0; i < 4; ++i) {
        const int row = row0 + ty * 4 + i;
        const int col = col0 + tx * 4;
        float4 v;
        float vals[4];
#pragma unroll
        for (int j = 0; j < 4; ++j) {
            float val = acc[i][j];
            if (BIAS) val += bias[col + j];
            if (RELU) val = fmaxf(val, 0.f);
            vals[j] = val;
        }
        v.x = vals[0]; v.y = vals[1]; v.z = vals[2]; v.w = vals[3];
        *(float4*)&C[row * N + col] = v;
    }
}

// ---------------------------------------------------------------------------
// Attention diagonal-softmax kernel.
// Q,K viewed as (32 heads) x 1024 rows x 512, head (b,a) at row ba*1024
// of the global 32768 x 512 matrix.  Block = (row-tile of 64) x (head).
// Online softmax over 16 column tiles of 64; emit d[row] =
//   exp(l_diag - m) / sum_exp  per row.
// ---------------------------------------------------------------------------
__global__ __launch_bounds__(256) void attn_diag_kernel(const float* __restrict__ Q,
                                                        const float* __restrict__ K,
                                                        float* __restrict__ dv) {
    __shared__ float Qs[32][64];   // [k][row]
    __shared__ float Ks[32][64];   // [k][col-row]
    __shared__ float red[64][16];
    __shared__ float m_run[64], s_run[64], diagv[64], mnew[64];

    const int tid = threadIdx.x;
    const int tx = tid & 15;
    const int ty = tid >> 4;
    const int rtile = blockIdx.x;   // 0..15
    const int ba = blockIdx.y;      // 0..31
    const int qrow0 = ba * 1024 + rtile * 64;
    const int krow0 = ba * 1024;
    const float invs = 0.04419417382415922f;  // 1/sqrt(512)

    if (tid < 64) { m_run[tid] = -1e30f; s_run[tid] = 0.f; }

    for (int ct = 0; ct < 16; ++ct) {
        float acc[4][4] = {};
        for (int kk = 0; kk < 512; kk += 32) {
            __syncthreads();
#pragma unroll
            for (int l = 0; l < 2; ++l) {
                const int u = tid * 2 + l;
                const int r = u >> 3;
                const int kq = (u & 7) * 4;
                float4 qv = *(const float4*)&Q[(qrow0 + r) * 512 + kk + kq];
                Qs[kq + 0][r] = qv.x; Qs[kq + 1][r] = qv.y;
                Qs[kq + 2][r] = qv.z; Qs[kq + 3][r] = qv.w;
                float4 kv = *(const float4*)&K[(krow0 + ct * 64 + r) * 512 + kk + kq];
                Ks[kq + 0][r] = kv.x; Ks[kq + 1][r] = kv.y;
                Ks[kq + 2][r] = kv.z; Ks[kq + 3][r] = kv.w;
            }
            __syncthreads();
#pragma unroll
            for (int k = 0; k < 32; ++k) {
                float4 a4 = *(const float4*)&Qs[k][ty * 4];
                float4 b4 = *(const float4*)&Ks[k][tx * 4];
                const float a[4] = {a4.x, a4.y, a4.z, a4.w};
                const float b[4] = {b4.x, b4.y, b4.z, b4.w};
#pragma unroll
                for (int i = 0; i < 4; ++i)
#pragma unroll
                    for (int j = 0; j < 4; ++j)
                        acc[i][j] = fmaf(a[i], b[j], acc[i][j]);
            }
        }
        // scale logits
#pragma unroll
        for (int i = 0; i < 4; ++i)
#pragma unroll
            for (int j = 0; j < 4; ++j) acc[i][j] *= invs;

        // capture diagonal (global col == global row happens when ct == rtile)
        if (ct == rtile) {
#pragma unroll
            for (int i = 0; i < 4; ++i) {
                const int R = ty * 4 + i;
                const int c = R - tx * 4;
                if (c >= 0 && c < 4) diagv[R] = acc[i][c];
            }
        }

        // per-row tile max
#pragma unroll
        for (int i = 0; i < 4; ++i) {
            float mx = fmaxf(fmaxf(acc[i][0], acc[i][1]),
                             fmaxf(acc[i][2], acc[i][3]));
            red[ty * 4 + i][tx] = mx;
        }
        __syncthreads();
        if (tid < 64) {
            float m = red[tid][0];
#pragma unroll
            for (int j = 1; j < 16; ++j) m = fmaxf(m, red[tid][j]);
            const float mo = m_run[tid];
            const float mn = fmaxf(mo, m);
            mnew[tid] = mn;
            s_run[tid] *= __expf(mo - mn);
            m_run[tid] = mn;
        }
        __syncthreads();
#pragma unroll
        for (int i = 0; i < 4; ++i) {
            const int R = ty * 4 + i;
            const float mn = mnew[R];
            float p = __expf(acc[i][0] - mn) + __expf(acc[i][1] - mn) +
                      __expf(acc[i][2] - mn) + __expf(acc[i][3] - mn);
            red[R][tx] = p;
        }
        __syncthreads();
        if (tid < 64) {
            float s = 0.f;
#pragma unroll
            for (int j = 0; j < 16; ++j) s += red[tid][j];
            s_run[tid] += s;
        }
        // next iteration's first __syncthreads() protects LDS reuse
    }
    __syncthreads();
    if (tid < 64) {
        dv[ba * 1024 + rtile * 64 + tid] =
            __expf(diagv[tid] - m_run[tid]) / s_run[tid];
    }
}

// ---------------------------------------------------------------------------
// In-place scale of V rows by d:  V[row,:] *= d[row], rows of 512 floats.
// ---------------------------------------------------------------------------
__global__ __launch_bounds__(256) void scale_v_kernel(float* __restrict__ V,
                                                      const float* __restrict__ d,
                                                      int total4) {
    const int idx = blockIdx.x * 256 + threadIdx.x;
    if (idx >= total4) return;
    const int row = idx >> 7;  // 128 float4 per 512-float row
    const float s = d[row];
    float4 v = ((const float4*)V)[idx];
    v.x *= s; v.y *= s; v.z *= s; v.w *= s;
    ((float4*)V)[idx] = v;
}

// ---------------------------------------------------------------------------
// Fused residual-add + LayerNorm over rows of 512.
// out[r,:] = LN(A[r,:] + Bv[r,:]) * g + be
// ---------------------------------------------------------------------------
__global__ __launch_bounds__(256) void add_ln_kernel(const float* __restrict__ A,
                                                     const float* __restrict__ Bv,
                                                     const float* __restrict__ g,
                                                     const float* __restrict__ be,
                                                     float* __restrict__ out) {
    __shared__ float sred[8];
    __shared__ float sred2[8];
    const int row = blockIdx.x;
    const int tid = threadIdx.x;
    const float* a = A + row * 512;
    const float* b = Bv + row * 512;

    const float v0 = a[tid] + b[tid];
    const float v1 = a[tid + 256] + b[tid + 256];
    float sum = v0 + v1;
    float sq = v0 * v0 + v1 * v1;
#pragma unroll
    for (int off = 32; off > 0; off >>= 1) {
        sum += __shfl_down(sum, off, 64);
        sq += __shfl_down(sq, off, 64);
    }
    const int wave = tid >> 6;
    if ((tid & 63) == 0) { sred[wave] = sum; sred2[wave] = sq; }
    __syncthreads();
    if (tid == 0) {
        float s = 0.f, q = 0.f;
#pragma unroll
        for (int w = 0; w < 4; ++w) { s += sred[w]; q += sred2[w]; }
        const float mu = s * (1.f / 512.f);
        const float var = q * (1.f / 512.f) - mu * mu;
        sred[4] = mu;
        sred2[4] = rsqrtf(var + LN_EPS);
    }
    __syncthreads();
    const float mu = sred[4];
    const float rs = sred2[4];
    out[row * 512 + tid] = (v0 - mu) * rs * g[tid] + be[tid];
    out[row * 512 + tid + 256] = (v1 - mu) * rs * g[tid + 256] + be[tid + 256];
}

// ---------------------------------------------------------------------------
// Launcher
// ---------------------------------------------------------------------------
extern "C" void kernel_launch(void* const* d_in, const int* in_sizes, int n_in,
                              void* d_out, int out_size, void* d_ws, size_t ws_size,
                              hipStream_t stream) {
    const float* x     = (const float*)d_in[0];
    const float* Wq    = (const float*)d_in[1];
    const float* Wk    = (const float*)d_in[2];
    const float* Wv    = (const float*)d_in[3];
    const float* Wo    = (const float*)d_in[4];
    const float* g1    = (const float*)d_in[5];
    const float* beta1 = (const float*)d_in[6];
    const float* Wf1   = (const float*)d_in[7];
    const float* bf1   = (const float*)d_in[8];
    const float* Wf2   = (const float*)d_in[9];
    const float* bf2   = (const float*)d_in[10];
    const float* g2    = (const float*)d_in[11];
    const float* beta2 = (const float*)d_in[12];
    float* out = (float*)d_out;

    float* ws = (float*)d_ws;
    float* Pq   = ws;                    // 4096x4096
    float* Pk   = Pq + 16777216;         // 4096x4096
    float* Pv   = Pk + 16777216;         // 4096x4096 (becomes hh in place)
    float* dvec = Pv + 16777216;         // 32768
    float* attn = dvec + 32768;          // 4096x512
    float* y1   = attn + 2097152;        // 4096x512
    float* f1   = y1 + 2097152;          // 4096x2048
    float* ff   = f1 + 8388608;          // 4096x512

    const int M = 4096;  // B*T

    // 1-3. QKV projections: (4096x512)@(512x4096)
    {
        dim3 grid(4096 / 64, M / 64), block(256);
        gemm64<false, false><<<grid, block, 0, stream>>>(x, Wq, nullptr, Pq, M, 4096, 512);
        gemm64<false, false><<<grid, block, 0, stream>>>(x, Wk, nullptr, Pk, M, 4096, 512);
        gemm64<false, false><<<grid, block, 0, stream>>>(x, Wv, nullptr, Pv, M, 4096, 512);
    }

    // 4. diagonal softmax values
    {
        dim3 grid(16, 32), block(256);
        attn_diag_kernel<<<grid, block, 0, stream>>>(Pq, Pk, dvec);
    }

    // 5. hh = d * V (in place on Pv); layout already correct for @Wo
    {
        const int total4 = 32768 * 512 / 4;
        scale_v_kernel<<<dim3(total4 / 256), dim3(256), 0, stream>>>(Pv, dvec, total4);
    }

    // 6. attn = hh2 @ Wo : (4096x4096)@(4096x512)
    {
        dim3 grid(512 / 64, M / 64), block(256);
        gemm64<false, false><<<grid, block, 0, stream>>>(Pv, Wo, nullptr, attn, M, 512, 4096);
    }

    // 7. y1 = LN(x + attn)
    add_ln_kernel<<<dim3(M), dim3(256), 0, stream>>>(x, attn, g1, beta1, y1);

    // 8. f1 = relu(y1 @ Wf1 + bf1) : (4096x512)@(512x2048)
    {
        dim3 grid(2048 / 64, M / 64), block(256);
        gemm64<true, true><<<grid, block, 0, stream>>>(y1, Wf1, bf1, f1, M, 2048, 512);
    }

    // 9. ff = f1 @ Wf2 + bf2 : (4096x2048)@(2048x512)
    {
        dim3 grid(512 / 64, M / 64), block(256);
        gemm64<true, false><<<grid, block, 0, stream>>>(f1, Wf2, bf2, ff, M, 512, 2048);
    }

    // 10. out = LN(y1 + ff)
    add_ln_kernel<<<dim3(M), dim3(256), 0, stream>>>(y1, ff, g2, beta2, out);
}

// Round 2
// 362.420 us; speedup vs baseline: 5.0619x; 5.0619x over previous
//
#include <hip/hip_runtime.h>
#include <stdint.h>

// ---------------------------------------------------------------------------
// H=512, N=8, B=4, T=1024.  All GEMMs as bf16 MFMA (m97 structure):
//   A [M][K] bf16 row-major, Bt [N][K] bf16 row-major (B transposed),
//   128x128 tile, BK=32, 4 waves (2x2), 4x4 fragments of 16x16x32 MFMA,
//   global_load_lds width-16 staging, 2-barrier K-loop.
// Attention: softmax row-sums + diagonal computed in the logits GEMM epilogue
//   (no S materialization; scaled logits are tiny so exp needs no max-shift).
// ---------------------------------------------------------------------------

#define LN_EPS 1e-5f

typedef __attribute__((ext_vector_type(8))) short short8;
typedef __attribute__((ext_vector_type(4))) float f32x4;

__device__ __forceinline__ unsigned short f2bf(float f) {
    unsigned int u = __float_as_uint(f);
    u = (u + 0x7fffu + ((u >> 16) & 1u)) >> 16;
    return (unsigned short)u;
}
__device__ __forceinline__ float bf2f(unsigned short h) {
    return __uint_as_float(((unsigned int)h) << 16);
}

__device__ __forceinline__ void llds16(const void* g, void* l) {
    __builtin_amdgcn_global_load_lds(
        (const __attribute__((address_space(1))) void*)g,
        (__attribute__((address_space(3))) void*)l, 16, 0, 0);
}

#define OUT_F32 0
#define OUT_BF16 1
#define OUT_ATTN 2

// ---------------------------------------------------------------------------
// bf16 MFMA GEMM: C = act(A @ Bt^T + bias).  M,N multiples of 128; K of 32.
// ---------------------------------------------------------------------------
template <int MODE, bool BIAS, bool RELU>
__global__ __launch_bounds__(256) void gemm_bt(
    const unsigned short* __restrict__ A,   // [M][K] bf16
    const unsigned short* __restrict__ Bt,  // [N][K] bf16
    const float* __restrict__ bias,         // [N] f32
    void* __restrict__ Cv,                  // [M][N] f32 or bf16 (unused ATTN)
    float* __restrict__ dsum,               // ATTN: [32768] f32 (pre-zeroed)
    float* __restrict__ ddiag,              // ATTN: [32768] f32
    int M, int N, int K,
    long aBatch, long bBatch, float scale) {
    __shared__ unsigned short As[128 * 32];  // [row][k] 64B rows
    __shared__ unsigned short Bs[128 * 32];

    const int tid = threadIdx.x;
    const int wid = tid >> 6;
    const int lane = tid & 63;
    const int lr = lane & 15;   // fragment row/col within 16
    const int kg = lane >> 4;   // k-group 0..3
    const int wr = wid >> 1;
    const int wc = wid & 1;
    const int row0 = blockIdx.y * 128;
    const int col0 = blockIdx.x * 128;

    const unsigned short* Ab = A + (long)blockIdx.z * aBatch;
    const unsigned short* Bb = Bt + (long)blockIdx.z * bBatch;

    // staging: per wave 2 calls of 1KB each for A and B
    const int rS = wid * 32 + (lane >> 2);  // row in 128-tile (call 0)
    const int k8 = (lane & 3) * 8;          // bf16 offset within 32-k row
    unsigned short* ldsA0 = &As[(wid * 2 + 0) * 512];
    unsigned short* ldsA1 = &As[(wid * 2 + 1) * 512];
    unsigned short* ldsB0 = &Bs[(wid * 2 + 0) * 512];
    unsigned short* ldsB1 = &Bs[(wid * 2 + 1) * 512];
    const unsigned short* gA0 = Ab + (long)(row0 + rS) * K + k8;
    const unsigned short* gA1 = gA0 + (long)16 * K;
    const unsigned short* gB0 = Bb + (long)(col0 + rS) * K + k8;
    const unsigned short* gB1 = gB0 + (long)16 * K;

    f32x4 acc[4][4];
#pragma unroll
    for (int m = 0; m < 4; ++m)
#pragma unroll
        for (int n = 0; n < 4; ++n)
#pragma unroll
            for (int j = 0; j < 4; ++j) acc[m][n][j] = 0.f;

    for (int kk = 0; kk < K; kk += 32) {
        __syncthreads();  // previous ds_reads done before overwrite
        llds16(gA0 + kk, ldsA0);
        llds16(gA1 + kk, ldsA1);
        llds16(gB0 + kk, ldsB0);
        llds16(gB1 + kk, ldsB1);
        __syncthreads();  // drains vmcnt -> LDS tiles ready
        short8 a[4], b[4];
#pragma unroll
        for (int m = 0; m < 4; ++m)
            a[m] = *(const short8*)&As[(wr * 64 + m * 16 + lr) * 32 + kg * 8];
#pragma unroll
        for (int n = 0; n < 4; ++n)
            b[n] = *(const short8*)&Bs[(wc * 64 + n * 16 + lr) * 32 + kg * 8];
#pragma unroll
        for (int m = 0; m < 4; ++m)
#pragma unroll
            for (int n = 0; n < 4; ++n)
                acc[m][n] = __builtin_amdgcn_mfma_f32_16x16x32_bf16(
                    a[m], b[n], acc[m][n], 0, 0, 0);
    }

    if (MODE == OUT_ATTN) {
        // rows of this wave: row0 + wr*64 + m*16 + kg*4 + j  (per head bz)
        const int hrow0 = blockIdx.z * 1024 + row0 + wr * 64;
        const bool diagblk = (blockIdx.x == blockIdx.y) && (wr == wc);
#pragma unroll
        for (int m = 0; m < 4; ++m) {
            float es[4] = {0.f, 0.f, 0.f, 0.f};
#pragma unroll
            for (int n = 0; n < 4; ++n) {
#pragma unroll
                for (int j = 0; j < 4; ++j) {
                    float e = __expf(acc[m][n][j] * scale);
                    es[j] += e;
                    if (diagblk && n == m && lr == kg * 4 + j)
                        ddiag[hrow0 + m * 16 + kg * 4 + j] = e;
                }
            }
#pragma unroll
            for (int j = 0; j < 4; ++j) {
                float s = es[j];
                s += __shfl_xor(s, 1, 64);
                s += __shfl_xor(s, 2, 64);
                s += __shfl_xor(s, 4, 64);
                s += __shfl_xor(s, 8, 64);
                if (lr == 0) atomicAdd(&dsum[hrow0 + m * 16 + kg * 4 + j], s);
            }
        }
        return;
    }

#pragma unroll
    for (int m = 0; m < 4; ++m) {
        const int grow = row0 + wr * 64 + m * 16 + kg * 4;
#pragma unroll
        for (int n = 0; n < 4; ++n) {
            const int gcol = col0 + wc * 64 + n * 16 + lr;
            const float bv = BIAS ? bias[gcol] : 0.f;
#pragma unroll
            for (int j = 0; j < 4; ++j) {
                float v = acc[m][n][j] + bv;
                if (RELU) v = fmaxf(v, 0.f);
                if (MODE == OUT_F32)
                    ((float*)Cv)[(long)(grow + j) * N + gcol] = v;
                else
                    ((unsigned short*)Cv)[(long)(grow + j) * N + gcol] = f2bf(v);
            }
        }
    }
}

// ---------------------------------------------------------------------------
// f32 [R][C] -> bf16 [C][R] transpose+convert (weights, once per launch)
// ---------------------------------------------------------------------------
__global__ __launch_bounds__(256) void transpose_bf16(
    const float* __restrict__ src, unsigned short* __restrict__ dst,
    int R, int C) {
    __shared__ float tile[32][33];
    const int tx = threadIdx.x & 31;
    const int ty = threadIdx.x >> 5;  // 0..7
    const int r0 = blockIdx.y * 32;
    const int c0 = blockIdx.x * 32;
#pragma unroll
    for (int k = 0; k < 4; ++k)
        tile[ty + k * 8][tx] = src[(long)(r0 + ty + k * 8) * C + c0 + tx];
    __syncthreads();
#pragma unroll
    for (int k = 0; k < 4; ++k)
        dst[(long)(c0 + ty + k * 8) * R + r0 + tx] = f2bf(tile[tx][ty + k * 8]);
}

// f32 -> bf16 flat convert, 8 elems/thread
__global__ __launch_bounds__(256) void convert_bf16(
    const float* __restrict__ src, unsigned short* __restrict__ dst, int n8) {
    const int idx = blockIdx.x * 256 + threadIdx.x;
    if (idx >= n8) return;
    float4 a = ((const float4*)src)[idx * 2];
    float4 b = ((const float4*)src)[idx * 2 + 1];
    uint4 o;
    o.x = (unsigned int)f2bf(a.x) | ((unsigned int)f2bf(a.y) << 16);
    o.y = (unsigned int)f2bf(a.z) | ((unsigned int)f2bf(a.w) << 16);
    o.z = (unsigned int)f2bf(b.x) | ((unsigned int)f2bf(b.y) << 16);
    o.w = (unsigned int)f2bf(b.z) | ((unsigned int)f2bf(b.w) << 16);
    ((uint4*)dst)[idx] = o;
}

// ---------------------------------------------------------------------------
// In-place diagonal-softmax scale of bf16 V rows (viewed [32768][512]):
//   V[r,:] *= ddiag[r]/dsum[r]
// ---------------------------------------------------------------------------
__global__ __launch_bounds__(256) void scale_v_kernel(
    unsigned short* __restrict__ V, const float* __restrict__ dsum,
    const float* __restrict__ ddiag, int nChunks) {
    const int idx = blockIdx.x * 256 + threadIdx.x;
    if (idx >= nChunks) return;
    const int row = idx >> 6;  // 64 chunks of 8 bf16 per 512-col row
    const float s = ddiag[row] / dsum[row];
    uint4 v = ((const uint4*)V)[idx];
    unsigned int w[4] = {v.x, v.y, v.z, v.w};
#pragma unroll
    for (int i = 0; i < 4; ++i) {
        const float lo = bf2f((unsigned short)(w[i] & 0xffffu)) * s;
        const float hi = bf2f((unsigned short)(w[i] >> 16)) * s;
        w[i] = (unsigned int)f2bf(lo) | ((unsigned int)f2bf(hi) << 16);
    }
    uint4 o;
    o.x = w[0]; o.y = w[1]; o.z = w[2]; o.w = w[3];
    ((uint4*)V)[idx] = o;
}

// ---------------------------------------------------------------------------
// Fused residual-add + LayerNorm (rows of 512); optional bf16 side-output.
// ---------------------------------------------------------------------------
template <bool WB>
__global__ __launch_bounds__(256) void add_ln_kernel(
    const float* __restrict__ A, const float* __restrict__ Bv,
    const float* __restrict__ g, const float* __restrict__ be,
    float* __restrict__ out, unsigned short* __restrict__ outb) {
    __shared__ float sred[8];
    __shared__ float sred2[8];
    const int row = blockIdx.x;
    const int tid = threadIdx.x;
    const float* a = A + (long)row * 512;
    const float* b = Bv + (long)row * 512;

    const float v0 = a[tid] + b[tid];
    const float v1 = a[tid + 256] + b[tid + 256];
    float sum = v0 + v1;
    float sq = v0 * v0 + v1 * v1;
#pragma unroll
    for (int off = 32; off > 0; off >>= 1) {
        sum += __shfl_down(sum, off, 64);
        sq += __shfl_down(sq, off, 64);
    }
    const int wave = tid >> 6;
    if ((tid & 63) == 0) { sred[wave] = sum; sred2[wave] = sq; }
    __syncthreads();
    if (tid == 0) {
        float s = 0.f, q = 0.f;
#pragma unroll
        for (int w = 0; w < 4; ++w) { s += sred[w]; q += sred2[w]; }
        const float mu = s * (1.f / 512.f);
        const float var = q * (1.f / 512.f) - mu * mu;
        sred[4] = mu;
        sred2[4] = rsqrtf(var + LN_EPS);
    }
    __syncthreads();
    const float mu = sred[4];
    const float rs = sred2[4];
    const float o0 = (v0 - mu) * rs * g[tid] + be[tid];
    const float o1 = (v1 - mu) * rs * g[tid + 256] + be[tid + 256];
    out[(long)row * 512 + tid] = o0;
    out[(long)row * 512 + tid + 256] = o1;
    if (WB) {
        outb[(long)row * 512 + tid] = f2bf(o0);
        outb[(long)row * 512 + tid + 256] = f2bf(o1);
    }
}

// ---------------------------------------------------------------------------
// Launcher
// ---------------------------------------------------------------------------
extern "C" void kernel_launch(void* const* d_in, const int* in_sizes, int n_in,
                              void* d_out, int out_size, void* d_ws, size_t ws_size,
                              hipStream_t stream) {
    const float* x     = (const float*)d_in[0];
    const float* Wq    = (const float*)d_in[1];
    const float* Wk    = (const float*)d_in[2];
    const float* Wv    = (const float*)d_in[3];
    const float* Wo    = (const float*)d_in[4];
    const float* g1    = (const float*)d_in[5];
    const float* beta1 = (const float*)d_in[6];
    const float* Wf1   = (const float*)d_in[7];
    const float* bf1   = (const float*)d_in[8];
    const float* Wf2   = (const float*)d_in[9];
    const float* bf2   = (const float*)d_in[10];
    const float* g2    = (const float*)d_in[11];
    const float* beta2 = (const float*)d_in[12];
    float* out = (float*)d_out;

    char* p = (char*)d_ws;
    unsigned short* xb   = (unsigned short*)p; p += (long)4096 * 512 * 2;
    unsigned short* WqT  = (unsigned short*)p; p += (long)4096 * 512 * 2;
    unsigned short* WkT  = (unsigned short*)p; p += (long)4096 * 512 * 2;
    unsigned short* WvT  = (unsigned short*)p; p += (long)4096 * 512 * 2;
    unsigned short* WoT  = (unsigned short*)p; p += (long)512 * 4096 * 2;
    unsigned short* Wf1T = (unsigned short*)p; p += (long)2048 * 512 * 2;
    unsigned short* Wf2T = (unsigned short*)p; p += (long)512 * 2048 * 2;
    unsigned short* Qb   = (unsigned short*)p; p += (long)4096 * 4096 * 2;
    unsigned short* Kb   = (unsigned short*)p; p += (long)4096 * 4096 * 2;
    unsigned short* Vb   = (unsigned short*)p; p += (long)4096 * 4096 * 2;
    float* dsum  = (float*)p; p += (long)32768 * 4;
    float* ddiag = (float*)p; p += (long)32768 * 4;
    float* attn  = (float*)p; p += (long)4096 * 512 * 4;
    float* y1    = (float*)p; p += (long)4096 * 512 * 4;
    unsigned short* y1b = (unsigned short*)p; p += (long)4096 * 512 * 2;
    unsigned short* f1b = (unsigned short*)p; p += (long)4096 * 2048 * 2;
    float* ff    = (float*)p; p += (long)4096 * 512 * 4;

    const dim3 blk(256);
    const float invs = 0.04419417382415922f;  // 1/sqrt(512)

    // 0. converts / weight transposes (bf16, B^T form)
    convert_bf16<<<dim3(1024), blk, 0, stream>>>(x, xb, 4096 * 512 / 8);
    transpose_bf16<<<dim3(4096 / 32, 512 / 32), blk, 0, stream>>>(Wq, WqT, 512, 4096);
    transpose_bf16<<<dim3(4096 / 32, 512 / 32), blk, 0, stream>>>(Wk, WkT, 512, 4096);
    transpose_bf16<<<dim3(4096 / 32, 512 / 32), blk, 0, stream>>>(Wv, WvT, 512, 4096);
    transpose_bf16<<<dim3(512 / 32, 4096 / 32), blk, 0, stream>>>(Wo, WoT, 4096, 512);
    transpose_bf16<<<dim3(2048 / 32, 512 / 32), blk, 0, stream>>>(Wf1, Wf1T, 512, 2048);
    transpose_bf16<<<dim3(512 / 32, 2048 / 32), blk, 0, stream>>>(Wf2, Wf2T, 2048, 512);

    // 1. QKV projections (bf16 out)
    gemm_bt<OUT_BF16, false, false><<<dim3(32, 32, 1), blk, 0, stream>>>(
        xb, WqT, nullptr, Qb, nullptr, nullptr, 4096, 4096, 512, 0, 0, 1.f);
    gemm_bt<OUT_BF16, false, false><<<dim3(32, 32, 1), blk, 0, stream>>>(
        xb, WkT, nullptr, Kb, nullptr, nullptr, 4096, 4096, 512, 0, 0, 1.f);
    gemm_bt<OUT_BF16, false, false><<<dim3(32, 32, 1), blk, 0, stream>>>(
        xb, WvT, nullptr, Vb, nullptr, nullptr, 4096, 4096, 512, 0, 0, 1.f);

    // 2. logits + softmax row-sums/diag (Q,K viewed [32 heads][1024][512])
    hipMemsetAsync(dsum, 0, 32768 * sizeof(float), stream);
    gemm_bt<OUT_ATTN, false, false><<<dim3(8, 8, 32), blk, 0, stream>>>(
        Qb, Kb, nullptr, nullptr, dsum, ddiag, 1024, 1024, 512,
        (long)1024 * 512, (long)1024 * 512, invs);

    // 3. hh = diag(attn) * V, in place on Vb
    scale_v_kernel<<<dim3(32768 * 512 / 8 / 256), blk, 0, stream>>>(
        Vb, dsum, ddiag, 32768 * 512 / 8);

    // 4. attn = hh @ Wo
    gemm_bt<OUT_F32, false, false><<<dim3(4, 32, 1), blk, 0, stream>>>(
        Vb, WoT, nullptr, attn, nullptr, nullptr, 4096, 512, 4096, 0, 0, 1.f);

    // 5. y1 = LN(x + attn)  (+ bf16 copy)
    add_ln_kernel<true><<<dim3(4096), blk, 0, stream>>>(x, attn, g1, beta1, y1, y1b);

    // 6. f1 = relu(y1 @ Wf1 + bf1)  (bf16 out)
    gemm_bt<OUT_BF16, true, true><<<dim3(16, 32, 1), blk, 0, stream>>>(
        y1b, Wf1T, bf1, f1b, nullptr, nullptr, 4096, 2048, 512, 0, 0, 1.f);

    // 7. ff = f1 @ Wf2 + bf2
    gemm_bt<OUT_F32, true, false><<<dim3(4, 32, 1), blk, 0, stream>>>(
        f1b, Wf2T, bf2, ff, nullptr, nullptr, 4096, 512, 2048, 0, 0, 1.f);

    // 8. out = LN(y1 + ff)
    add_ln_kernel<false><<<dim3(4096), blk, 0, stream>>>(y1, ff, g2, beta2, out, nullptr);
}